// Round 12
// baseline (69.002 us; speedup 1.0000x reference)
//
#include <hip/hip_runtime.h>

namespace {

constexpr int   kT = 512, kC = 512, kL = 128, kBlank = 511;
constexpr int   kCH  = 16;         // rows per chunk
constexpr int   kNCH = kT / kCH;   // 32 chunks
constexpr float kEps = 1e-7f, kLn2 = 0.6931471805599453f;

typedef float __attribute__((address_space(1))) f32g;
typedef float __attribute__((address_space(3))) f32l;

// Coalesced width-16 global->LDS: 64 lanes x 16B = 1KB (half a row).
__device__ __forceinline__ void glds16(const float* g, float* l) {
    __builtin_amdgcn_global_load_lds((const f32g*)g, (f32l*)l, 16, 0, 0);
}
__device__ __forceinline__ float rlane(float x, int l) {
    return __int_as_float(__builtin_amdgcn_readlane(__float_as_int(x), l));
}
__device__ __forceinline__ float bperm(int a, float x) {
    return __int_as_float(__builtin_amdgcn_ds_bpermute(a, __float_as_int(x)));
}
__device__ __forceinline__ float LOG2(float x) { return __builtin_amdgcn_logf(x); }

// Raw barrier: no compiler-inserted vmcnt(0) drain (unlike __syncthreads).
// Proven pattern (8-phase template): loads stay in flight across s_barrier.
__device__ __forceinline__ void barrier_raw() {
    asm volatile("" ::: "memory");
    __builtin_amdgcn_s_barrier();
    asm volatile("" ::: "memory");
}

__global__ __launch_bounds__(128, 1) void ctc_fwd_kernel(
        const int* __restrict__ labels,
        const float* __restrict__ y_pred,
        float* __restrict__ out) {
    __shared__ __align__(16) float buf[3][kCH][kC];   // 96 KiB chunk ring

    const int tid  = (int)threadIdx.x;
    const int lane = tid & 63;
    const int wv   = tid >> 6;           // 0 = consumer, 1 = producer
    const int b    = (int)blockIdx.x;
    const float* yp  = y_pred + (size_t)b * kT * kC;
    const int*   lab = labels + b * kL;

    // ---- consumer constants: state s = 4*lane + k (k=0..3), + scalar 256 ----
    int   cls1 = kBlank, cls3 = kBlank;
    float skp1 = 0.f, skp3 = 0.f;
    if (wv == 0) {
        cls1 = lab[2 * lane];
        cls3 = lab[2 * lane + 1];
        skp1 = (lane >= 1 && lab[2 * lane] != lab[2 * lane - 1]) ? 1.f : 0.f;
        skp3 = (lab[2 * lane + 1] != lab[2 * lane]) ? 1.f : 0.f;
    }
    const int addr1 = (lane - 1) << 2;   // bpermute: lane i <- lane i-1

    // rotating ring pointers (register-level, no dynamic LDS indexing)
    float (*bC)[kC] = buf[0];   // chunk c   (consumer reads)
    float (*bN)[kC] = buf[1];   // chunk c+1 (resident after this iter's wait)
    float (*bP)[kC] = buf[2];   // chunk c+2 (being filled, in flight)

    // ---- prologue: producer issues chunks 0,1; waits only for chunk 0 ----
    if (wv == 1) {
        for (int r = 0; r < kCH; ++r) {
            const float* row = yp + (size_t)r * kC;
            glds16(row + lane * 4,       &bC[r][0]);
            glds16(row + 256 + lane * 4, &bC[r][256]);
        }
        for (int r = 0; r < kCH; ++r) {
            const float* row = yp + (size_t)(kCH + r) * kC;
            glds16(row + lane * 4,       &bN[r][0]);
            glds16(row + 256 + lane * 4, &bN[r][256]);
        }
        asm volatile("s_waitcnt vmcnt(32)" ::: "memory");   // chunk 0 resident
    }
    barrier_raw();

    // ---- linear-domain scaled forward state ----
    float a0 = 0.f, a1 = 0.f, a2 = 0.f, a3 = 0.f, a256 = 0.f, etot = 0.f;

    for (int c = 0; c < kNCH; ++c) {
        if (wv == 1) {
            if (c + 2 < kNCH) {
                // issue chunk c+2 FIRST (stays in flight across the barrier),
                // then wait for chunk c+1 only (counted, never 0 here).
                for (int r = 0; r < kCH; ++r) {
                    const float* row = yp + (size_t)((c + 2) * kCH + r) * kC;
                    glds16(row + lane * 4,       &bP[r][0]);
                    glds16(row + 256 + lane * 4, &bP[r][256]);
                }
                asm volatile("s_waitcnt vmcnt(32)" ::: "memory");
            } else if (c + 1 < kNCH) {
                asm volatile("s_waitcnt vmcnt(0)" ::: "memory"); // tail, once
            }
        } else {
            // ---- consumer: 16 recurrence steps from bC (r11 body) ----
            int rs = 0;
            if (c == 0) {
                const float pb0 = bC[0][kBlank] + kEps;
                const float pl0 = bC[0][cls1] + kEps;   // lane0: lab[0]
                a0 = (lane == 0) ? pb0 : 0.f;           // state 0
                a1 = (lane == 0) ? pl0 : 0.f;           // state 1
                rs = 1;
            }
            float rb = bC[rs][kBlank];   // same-address broadcast (blank)
            float r1 = bC[rs][cls1];
            float r3 = bC[rs][cls3];
            for (int r = rs; r < kCH; ++r) {
                float nb = rb, n1 = r1, n3 = r3;
                if (r + 1 < kCH) {       // prefetch next row's probs
                    nb = bC[r + 1][kBlank];
                    n1 = bC[r + 1][cls1];
                    n3 = bC[r + 1][cls3];
                }
                const float pb = rb + kEps;   // blank prob (k=0 and k=2)
                const float p1 = r1 + kEps;
                const float p3 = r3 + kEps;
                float sh3 = bperm(addr1, a3);          // prev-lane a3 (state 4l-1)
                sh3 = (lane == 0) ? 0.f : sh3;
                const float a255 = rlane(a3, 63);      // state 255 (pre-update)
                const float b0 = (a0 + sh3) * pb;                // s=4l (blank)
                const float b1 = (a1 + a0 + skp1 * sh3) * p1;    // s=4l+1
                const float b2 = (a2 + a1) * pb;                 // s=4l+2 (blank)
                const float b3 = (a3 + a2 + skp3 * a1) * p3;     // s=4l+3
                a256 = (a256 + a255) * pb;                       // s=256 (blank)
                a0 = b0; a1 = b1; a2 = b2; a3 = b3;
                rb = nb; r1 = n1; r3 = n3;
            }
            // ---- lossless power-of-2 renorm every 2 chunks (32 steps) ----
            if (c & 1) {
                float m = fmaxf(fmaxf(a0, a1), fmaxf(a2, a3));
#pragma unroll
                for (int i = 1; i < 64; i <<= 1) m = fmaxf(m, __shfl_xor(m, i));
                m = fmaxf(m, a256);
                const int ex = (__float_as_int(m) >> 23) & 0xFF;
                if (ex > 1) {
                    const float sc = __int_as_float((254 - ex) << 23); // 2^(127-ex)
                    a0 *= sc; a1 *= sc; a2 *= sc; a3 *= sc; a256 *= sc;
                    etot += (float)(ex - 127);
                }
            }
        }
        barrier_raw();
        // rotate ring: c+1 becomes current, c+2 becomes next, old current is
        // the new fill target (its data was fully consumed this iteration).
        float (*tmp)[kC] = bC; bC = bN; bN = bP; bP = tmp;
    }

    // ---- loss = -ln2 * (log2(alpha255 + alpha256) + etot) ----
    if (wv == 0) {
        const float a255 = rlane(a3, 63);   // state 255 = lane 63, k=3
        const float s    = a255 + a256;
        const float loss = -kLn2 * (LOG2(s) + etot);
        if (lane == 0) out[b] = loss;
    }
}

} // namespace

extern "C" void kernel_launch(void* const* d_in, const int* in_sizes, int n_in,
                              void* d_out, int out_size, void* d_ws, size_t ws_size,
                              hipStream_t stream) {
    const int*   labels = (const int*)d_in[0];   // y_true [256,128] int32
    const float* y_pred = (const float*)d_in[1]; // y_pred [256,512,512] f32
    float*       out    = (float*)d_out;         // loss [256,1] f32
    (void)in_sizes; (void)n_in; (void)d_ws; (void)ws_size;
    hipLaunchKernelGGL(ctc_fwd_kernel, dim3(out_size), dim3(128), 0, stream,
                       labels, y_pred, out);
}

// Round 13
// 52.049 us; speedup vs baseline: 1.3257x; 1.3257x over previous
//
#include <hip/hip_runtime.h>

namespace {

constexpr int   kT = 512, kC = 512, kL = 128, kBlank = 511;
constexpr int   kCH  = 16;         // rows per chunk
constexpr int   kNCH = kT / kCH;   // 32 chunks
constexpr float kEps = 1e-7f, kLn2 = 0.6931471805599453f;

typedef float __attribute__((address_space(1))) f32g;
typedef float __attribute__((address_space(3))) f32l;

// Coalesced width-16 global->LDS: 64 lanes x 16B = 1KB (half a row).
__device__ __forceinline__ void glds16(const float* g, float* l) {
    __builtin_amdgcn_global_load_lds((const f32g*)g, (f32l*)l, 16, 0, 0);
}
__device__ __forceinline__ float rlane(float x, int l) {
    return __int_as_float(__builtin_amdgcn_readlane(__float_as_int(x), l));
}
__device__ __forceinline__ float bperm(int a, float x) {
    return __int_as_float(__builtin_amdgcn_ds_bpermute(a, __float_as_int(x)));
}
__device__ __forceinline__ float LOG2(float x) { return __builtin_amdgcn_logf(x); }

// Raw barrier: no compiler-inserted vmcnt(0) drain (unlike __syncthreads).
__device__ __forceinline__ void barrier_raw() {
    asm volatile("" ::: "memory");
    __builtin_amdgcn_s_barrier();
    asm volatile("" ::: "memory");
}

__global__ __launch_bounds__(128, 1) void ctc_fwd_kernel(
        const int* __restrict__ labels,
        const float* __restrict__ y_pred,
        float* __restrict__ out) {
    __shared__ __align__(16) float buf[2][kCH][kC];   // 64 KiB double buffer

    const int tid  = (int)threadIdx.x;
    const int lane = tid & 63;
    const int wv   = tid >> 6;           // 0 = consumer, 1 = producer
    const int b    = (int)blockIdx.x;
    const float* yp  = y_pred + (size_t)b * kT * kC;
    const int*   lab = labels + b * kL;

    // ---- consumer constants: state s = 4*lane + k (k=0..3), + scalar 256.
    // Producer wave loads NOTHING here: its vmcnt stream stays pure glds16.
    int   cls1 = kBlank, cls3 = kBlank;
    float skp1 = 0.f, skp3 = 0.f;
    if (wv == 0) {
        cls1 = lab[2 * lane];
        cls3 = lab[2 * lane + 1];
        skp1 = (lane >= 1 && lab[2 * lane] != lab[2 * lane - 1]) ? 1.f : 0.f;
        skp3 = (lab[2 * lane + 1] != lab[2 * lane]) ? 1.f : 0.f;
    }
    const int addr1 = (lane - 1) << 2;   // bpermute: lane i <- lane i-1

    // per-chunk register cache of gathered probs (the key change this round)
    float g_rb[kCH], g_r1[kCH], g_r3[kCH];

    // ---- prologue: producer issues chunks 0,1; waits for chunk 0 only ----
    if (wv == 1) {
        for (int r = 0; r < kCH; ++r) {
            const float* row = yp + (size_t)r * kC;
            glds16(row + lane * 4,       &buf[0][r][0]);
            glds16(row + 256 + lane * 4, &buf[0][r][256]);
        }
        for (int r = 0; r < kCH; ++r) {
            const float* row = yp + (size_t)(kCH + r) * kC;
            glds16(row + lane * 4,       &buf[1][r][0]);
            glds16(row + 256 + lane * 4, &buf[1][r][256]);
        }
        asm volatile("s_waitcnt vmcnt(32)" ::: "memory");   // chunk 0 resident
    }
    barrier_raw();
    if (wv == 0) {   // gather chunk 0 into registers
#pragma unroll
        for (int r = 0; r < kCH; ++r) {
            g_rb[r] = buf[0][r][kBlank];
            g_r1[r] = buf[0][r][cls1];
            g_r3[r] = buf[0][r][cls3];
        }
    }
    barrier_raw();   // protect buf[0] before producer overwrites it (c=0 ph1)

    // ---- linear-domain scaled forward; t=0 handled by injection (exact) ----
    float a0 = 0.f, a1 = 0.f, a2 = 0.f, a3 = 0.f, a256 = 0.f, etot = 0.f;
    float inj = (lane == 0) ? 1.f : 0.f;   // lane0-only, dies after first step

    for (int c = 0; c < kNCH; ++c) {
        // ======== phase 1 ========
        if (wv == 1) {
            if (c + 2 < kNCH) {
                // issue chunk c+2 into the buffer chunk c vacated (its values
                // live in consumer registers now), then counted wait: c+1
                // resident, c+2 stays in flight across the barrier.
                float (*bP)[kC] = buf[c & 1];
                for (int r = 0; r < kCH; ++r) {
                    const float* row = yp + (size_t)((c + 2) * kCH + r) * kC;
                    glds16(row + lane * 4,       &bP[r][0]);
                    glds16(row + 256 + lane * 4, &bP[r][256]);
                }
                asm volatile("s_waitcnt vmcnt(32)" ::: "memory");
            } else {
                asm volatile("s_waitcnt vmcnt(0)" ::: "memory");   // tail
            }
        } else {
            // 16 register-only recurrence steps; DS traffic = 16 bpermutes.
#pragma unroll
            for (int r = 0; r < kCH; ++r) {
                const float pb = g_rb[r] + kEps;   // blank prob (k=0,2,256)
                const float p1 = g_r1[r] + kEps;
                const float p3 = g_r3[r] + kEps;
                float sh3 = bperm(addr1, a3);      // prev-lane a3 (state 4l-1)
                sh3 = (lane == 0) ? 0.f : sh3;
                const float a255 = rlane(a3, 63);  // state 255 (pre-update)
                const float b0 = (a0 + sh3 + inj) * pb;              // s=4l
                const float b1 = (a1 + a0 + skp1 * sh3 + inj) * p1;  // s=4l+1
                const float b2 = (a2 + a1) * pb;                     // s=4l+2
                const float b3 = (a3 + a2 + skp3 * a1) * p3;         // s=4l+3
                a256 = (a256 + a255) * pb;                           // s=256
                a0 = b0; a1 = b1; a2 = b2; a3 = b3;
                inj = 0.f;
            }
            // lossless power-of-2 renorm every 2 chunks (32 steps)
            if (c & 1) {
                float m = fmaxf(fmaxf(a0, a1), fmaxf(a2, a3));
#pragma unroll
                for (int i = 1; i < 64; i <<= 1) m = fmaxf(m, __shfl_xor(m, i));
                m = fmaxf(m, a256);
                const int ex = (__float_as_int(m) >> 23) & 0xFF;
                if (ex > 1) {
                    const float sc = __int_as_float((254 - ex) << 23); // 2^(127-ex)
                    a0 *= sc; a1 *= sc; a2 *= sc; a3 *= sc; a256 *= sc;
                    etot += (float)(ex - 127);
                }
            }
        }
        barrier_raw();   // mid: chunk c+1 resident AND steps done
        // ======== phase 2: consumer gathers chunk c+1 into registers ========
        if (wv == 0 && c + 1 < kNCH) {
            float (*bG)[kC] = buf[(c + 1) & 1];
#pragma unroll
            for (int r = 0; r < kCH; ++r) {
                g_rb[r] = bG[r][kBlank];
                g_r1[r] = bG[r][cls1];
                g_r3[r] = bG[r][cls3];
            }
        }
        barrier_raw();   // end: gathers done before next phase-1 overwrite
    }

    // ---- loss = -ln2 * (log2(alpha255 + alpha256) + etot) ----
    if (wv == 0) {
        const float a255 = rlane(a3, 63);   // state 255 = lane 63, k=3
        const float s    = a255 + a256;
        const float loss = -kLn2 * (LOG2(s) + etot);
        if (lane == 0) out[b] = loss;
    }
}

} // namespace

extern "C" void kernel_launch(void* const* d_in, const int* in_sizes, int n_in,
                              void* d_out, int out_size, void* d_ws, size_t ws_size,
                              hipStream_t stream) {
    const int*   labels = (const int*)d_in[0];   // y_true [256,128] int32
    const float* y_pred = (const float*)d_in[1]; // y_pred [256,512,512] f32
    float*       out    = (float*)d_out;         // loss [256,1] f32
    (void)in_sizes; (void)n_in; (void)d_ws; (void)ws_size;
    hipLaunchKernelGGL(ctc_fwd_kernel, dim3(out_size), dim3(128), 0, stream,
                       labels, y_pred, out);
}